// Round 12
// baseline (134.694 us; speedup 1.0000x reference)
//
#include <hip/hip_runtime.h>
#include <hip/hip_bf16.h>
#include <math.h>

// MimiAttention: B=4, S=2048, HID=512, NH=8, HD=64, SW=250, theta=10000
// Round 23: revert r22 (128-row attn: -2 blocks/CU, +3.1us — attn needs
// block parallelism, 64-row/1024-block form locked). New: ELIMINATE the
// cvt_all kernel (+its dispatch gap, ~12-14us of the budget) by fusing
// fp32->bf16 conversion into the consumers:
//  - qkv: reg-staged fp32 X/W loads + in-reg cvt + swizzled ds_write_b128
//    (T14: next tile's loads issue before current MFMA phase). X/W slices
//    are L2-resident per XCD; 12x fp32 re-read is L2 traffic.
//  - out_proj: A operand stays glds16 (bf16 from attn); Wo tile reg-cvt.
// Same write-side swizzle phys = chunk ^ ((row>>1)&3); read side unchanged.
// attn = r16/r20 exact (1024 blocks, 64-row, verified).

#define B_   4
#define S_   2048
#define HID_ 512
#define NH_  8
#define HD_  64
#define SW_  250

typedef __bf16 bf16x8 __attribute__((ext_vector_type(8)));
typedef __bf16 bf16x4 __attribute__((ext_vector_type(4)));
typedef float f32x4 __attribute__((ext_vector_type(4)));
using bf16_t = __hip_bfloat16;
typedef unsigned int u32;

// async global->LDS, 16 B per lane (wave-uniform base + lane*16 semantics)
__device__ __forceinline__ void glds16(const void* g, void* l) {
    __builtin_amdgcn_global_load_lds(
        (const __attribute__((address_space(1))) u32*)g,
        (__attribute__((address_space(3))) u32*)l, 16, 0, 0);
}

__device__ __forceinline__ bf16x8 cvt8(float4 a, float4 b) {
    bf16x8 r;
    r[0] = (__bf16)a.x; r[1] = (__bf16)a.y; r[2] = (__bf16)a.z; r[3] = (__bf16)a.w;
    r[4] = (__bf16)b.x; r[5] = (__bf16)b.y; r[6] = (__bf16)b.z; r[7] = (__bf16)b.w;
    return r;
}

// ---------------------------------------------------------------------------
// Fused QKV GEMM with inline fp32->bf16 staging. 128x128 tile, BK=32.
// Staging: thread t owns row srow=t>>1 (of both A and B tiles), half
// shalf=t&1 (16 cols). Per K-step: 8 float4 fp32 loads -> cvt -> 4
// swizzled ds_write_b128. T14: t+1 loads issued before t's MFMA phase.
// Read side + RoPE epilogue = r20 exact. 768 1-D blocks, XCD-chunked.
// ---------------------------------------------------------------------------
__global__ __launch_bounds__(256) void qkv_gemm(
    const float* __restrict__ X,  const float* __restrict__ Wq,
    const float* __restrict__ Wk, const float* __restrict__ Wv,
    bf16_t* __restrict__ Q, bf16_t* __restrict__ Kbuf, bf16_t* __restrict__ Vt)
{
    __shared__ __align__(16) char smem_raw[34816];  // 16KB stage / 34KB epi
    bf16_t* const sm = (bf16_t*)smem_raw;
    bf16_t* const As = sm;            // 128*32 = 4096 elems (8 KB)
    bf16_t* const Bs = sm + 4096;     // 128*32 = 4096 elems (8 KB)
    const int tid = threadIdx.x;
    const int wave = tid >> 6, lane = tid & 63;
    const int quad = lane >> 4, l16 = lane & 15;
    const int wm = wave & 1, wn = wave >> 1;

    const int g = blockIdx.x;
    const int xcd = g & 7, slot = g >> 3;          // slot in [0,96)
    const int mi = xcd * 8 + (slot & 7);           // [0,64)
    const int ni = slot >> 3;                      // [0,12)
    const int m0 = mi * 128, n0 = ni * 128;

    // staging addressing: row srow (both tiles), 16-col half shalf
    const int srow = tid >> 1, shalf = tid & 1;
    const int swz = (srow >> 1) & 3;
    const int pc0 = ((shalf * 2) ^ swz) * 8;
    const int pc1 = ((shalf * 2 + 1) ^ swz) * 8;
    const int seg = n0 >> 9;                       // 0=Q 1=K 2=V
    const float* Wsel = (seg == 0) ? Wq : (seg == 1) ? Wk : Wv;
    const float* xrow = X    + (size_t)(m0 + srow) * HID_ + shalf * 16;
    const float* wrow = Wsel + (size_t)((n0 & 511) + srow) * HID_ + shalf * 16;

    // prologue: load tile 0 into cur regs
    float4 a0, a1, a2, a3, b0, b1, b2, b3;
    a0 = *reinterpret_cast<const float4*>(xrow + 0);
    a1 = *reinterpret_cast<const float4*>(xrow + 4);
    a2 = *reinterpret_cast<const float4*>(xrow + 8);
    a3 = *reinterpret_cast<const float4*>(xrow + 12);
    b0 = *reinterpret_cast<const float4*>(wrow + 0);
    b1 = *reinterpret_cast<const float4*>(wrow + 4);
    b2 = *reinterpret_cast<const float4*>(wrow + 8);
    b3 = *reinterpret_cast<const float4*>(wrow + 12);

    f32x4 acc[4][4] = {};
    for (int t = 0; t < 16; ++t) {
        // issue next tile's fp32 loads early (hide under MFMA phase)
        float4 na0, na1, na2, na3, nb0, nb1, nb2, nb3;
        if (t + 1 < 16) {
            const int k1 = (t + 1) * 32;
            na0 = *reinterpret_cast<const float4*>(xrow + k1 + 0);
            na1 = *reinterpret_cast<const float4*>(xrow + k1 + 4);
            na2 = *reinterpret_cast<const float4*>(xrow + k1 + 8);
            na3 = *reinterpret_cast<const float4*>(xrow + k1 + 12);
            nb0 = *reinterpret_cast<const float4*>(wrow + k1 + 0);
            nb1 = *reinterpret_cast<const float4*>(wrow + k1 + 4);
            nb2 = *reinterpret_cast<const float4*>(wrow + k1 + 8);
            nb3 = *reinterpret_cast<const float4*>(wrow + k1 + 12);
        }
        // cvt + swizzled deposit of current tile
        *reinterpret_cast<bf16x8*>(&As[srow * 32 + pc0]) = cvt8(a0, a1);
        *reinterpret_cast<bf16x8*>(&As[srow * 32 + pc1]) = cvt8(a2, a3);
        *reinterpret_cast<bf16x8*>(&Bs[srow * 32 + pc0]) = cvt8(b0, b1);
        *reinterpret_cast<bf16x8*>(&Bs[srow * 32 + pc1]) = cvt8(b2, b3);
        __syncthreads();

        bf16x8 af[4], bfr[4];
#pragma unroll
        for (int i = 0; i < 4; ++i) {
            int ra = wm * 64 + i * 16 + l16;
            int rb = wn * 64 + i * 16 + l16;
            int pa = quad ^ ((ra >> 1) & 3);
            int pb = quad ^ ((rb >> 1) & 3);
            af[i]  = *reinterpret_cast<const bf16x8*>(&As[ra * 32 + pa * 8]);
            bfr[i] = *reinterpret_cast<const bf16x8*>(&Bs[rb * 32 + pb * 8]);
        }
#pragma unroll
        for (int mi2 = 0; mi2 < 4; ++mi2)
#pragma unroll
            for (int ni2 = 0; ni2 < 4; ++ni2)
                acc[mi2][ni2] = __builtin_amdgcn_mfma_f32_16x16x32_bf16(af[mi2], bfr[ni2], acc[mi2][ni2], 0, 0, 0);
        __syncthreads();
        a0 = na0; a1 = na1; a2 = na2; a3 = na3;
        b0 = nb0; b1 = nb1; b2 = nb2; b3 = nb3;
    }

    // ---- epilogue via wave-private 64x68 bf16 LDS tile (r20 exact) ----
    const int hh = ((n0 & 511) + wn * 64) >> 6;   // head of this wave
    bf16_t* wt = sm + wave * 4352;
    const int mbase = m0 + wm * 64;
    const int bb = mbase >> 11;
    const int sbase = mbase & (S_ - 1);

    if (seg < 2) {
        const float qs = (seg == 0) ? 0.125f : 1.0f;
        const float c = 0.41524101186f;           // log2(10000)/32
        float inv0 = exp2f(-(float)l16 * c);
        float inv1 = exp2f(-(float)(l16 + 16) * c);
#pragma unroll
        for (int mi2 = 0; mi2 < 4; ++mi2)
#pragma unroll
            for (int r = 0; r < 4; ++r) {
                int lrow = mi2 * 16 + quad * 4 + r;
                float sf = (float)(sbase + lrow);
#pragma unroll
                for (int ip = 0; ip < 2; ++ip) {
                    float sn, cs_;
                    __sincosf(sf * (ip ? inv1 : inv0), &sn, &cs_);
                    float x1 = acc[mi2][ip][r], x2 = acc[mi2][ip + 2][r];
                    wt[lrow * 68 + ip * 16 + l16]      = __float2bfloat16((x1 * cs_ - x2 * sn) * qs);
                    wt[lrow * 68 + ip * 16 + l16 + 32] = __float2bfloat16((x2 * cs_ + x1 * sn) * qs);
                }
            }
        bf16_t* Y = (seg == 0) ? Q : Kbuf;
#pragma unroll
        for (int it = 0; it < 8; ++it) {
            int e = it * 64 + lane;
            int sr = e >> 3, doff = (e & 7) * 8;
            size_t g2 = ((size_t)(bb * NH_ + hh) * S_ + sbase + sr) * HD_ + doff;
            *reinterpret_cast<bf16x8*>(Y + g2) =
                *reinterpret_cast<const bf16x8*>(wt + sr * 68 + doff);
        }
    } else {
#pragma unroll
        for (int mi2 = 0; mi2 < 4; ++mi2)
#pragma unroll
            for (int ni2 = 0; ni2 < 4; ++ni2)
#pragma unroll
                for (int r = 0; r < 4; ++r)
                    wt[(ni2 * 16 + l16) * 68 + mi2 * 16 + quad * 4 + r] =
                        __float2bfloat16(acc[mi2][ni2][r]);
#pragma unroll
        for (int it = 0; it < 8; ++it) {
            int e = it * 64 + lane;
            int d = e >> 3, soff = (e & 7) * 8;
            size_t g2 = ((size_t)(bb * NH_ + hh) * HD_ + d) * S_ + sbase + soff;
            *reinterpret_cast<bf16x8*>(Vt + g2) =
                *reinterpret_cast<const bf16x8*>(wt + d * 68 + soff);
        }
    }
}

// ---------------------------------------------------------------------------
// Attention (r16/r20 exact, verified): block = 64 q-rows, block-staged K/V
// double-buffer with counted vmcnt(2), one-pass no-max softmax. 1024 blocks.
// ---------------------------------------------------------------------------
__global__ __launch_bounds__(256) void attn_mfma(
    const bf16_t* __restrict__ Q, const bf16_t* __restrict__ K,
    const bf16_t* __restrict__ Vt, bf16_t* __restrict__ A)
{
    __shared__ __align__(16) __bf16 Ks[2][32 * 64];   // 2 x 4 KB
    __shared__ __align__(16) __bf16 Vs[2][64 * 32];   // 2 x 4 KB
    __shared__ __align__(16) __bf16 pt[4][16][40];    // per-wave P, 5 KB
    __shared__ float sums_l[4][16];
    const int tid = threadIdx.x;
    const int wave = tid >> 6, lane = tid & 63;
    const int quad = lane >> 4, l16 = lane & 15;

    const int g = blockIdx.x;
    const int xcd = g & 7, slot = g >> 3;          // slot in [0,128)
    const int bh = xcd * 4 + (slot >> 5);          // [0,32)
    const int qt = slot & 31;                      // q-block of 64 rows
    const int b = bh >> 3, h = bh & 7;
    const int q0b = qt * 64;
    const int q0 = q0b + wave * 16;

    const size_t bh_  = (size_t)(b * NH_ + h) * S_;
    const size_t bhd = (size_t)(b * NH_ + h) * HD_;

    bf16x8 qf0, qf1;
    {
        const bf16_t* qp = Q + (bh_ + q0 + l16) * HD_ + quad * 8;
        qf0 = *reinterpret_cast<const bf16x8*>(qp);
        qf1 = *reinterpret_cast<const bf16x8*>(qp + 32);
    }
    const int kstartB = (q0b > SW_) ? ((q0b - SW_) & ~31) : 0;
    const int ntB = (q0b + 95 - kstartB) >> 5;     // 2..12, block-uniform
    const int qq = q0 + l16;

    const int krow = tid >> 3, kl = (tid & 7) ^ (krow & 7);   // K stage addr
    const int vrow = tid >> 2, vl = (tid & 3) ^ (vrow & 3);   // V stage addr

    {
        const int kb = kstartB;
        glds16(K  + (bh_ + kb + krow) * HD_ + kl * 8, &Ks[0][tid * 8]);
        glds16(Vt + (bhd + vrow) * S_ + kb + vl * 8, &Vs[0][tid * 8]);
    }

    float sum = 0.f;
    f32x4 o[4] = {};
    for (int t = 0; t < ntB; ++t) {
        const int cur = t & 1;
        const int kb = kstartB + t * 32;
        if (t + 1 < ntB) {
            const int kb2 = kb + 32;
            glds16(K  + (bh_ + kb2 + krow) * HD_ + kl * 8, &Ks[cur ^ 1][tid * 8]);
            glds16(Vt + (bhd + vrow) * S_ + kb2 + vl * 8, &Vs[cur ^ 1][tid * 8]);
            asm volatile("s_waitcnt vmcnt(2)" ::: "memory");
        } else {
            asm volatile("s_waitcnt vmcnt(0)" ::: "memory");
        }
        __builtin_amdgcn_s_barrier();
        asm volatile("" ::: "memory");

#pragma unroll
        for (int half = 0; half < 2; ++half) {
            const int rowt = half * 16 + l16;
            const int p0 = quad ^ (rowt & 7);
            const int p1 = (quad ^ 4) ^ (rowt & 7);
            bf16x8 k0 = *reinterpret_cast<const bf16x8*>(&Ks[cur][rowt * 64 + p0 * 8]);
            bf16x8 k1 = *reinterpret_cast<const bf16x8*>(&Ks[cur][rowt * 64 + p1 * 8]);
            f32x4 z = {};
            z = __builtin_amdgcn_mfma_f32_16x16x32_bf16(k0, qf0, z, 0, 0, 0);
            z = __builtin_amdgcn_mfma_f32_16x16x32_bf16(k1, qf1, z, 0, 0, 0);
            const int kbase = kb + half * 16 + quad * 4;
            bf16x4 pk;
#pragma unroll
            for (int r = 0; r < 4; ++r) {
                int key = kbase + r;
                bool keep = (key <= qq) && (qq - key <= SW_);
                float p = keep ? __expf(z[r]) : 0.f;
                sum += p;
                pk[r] = (__bf16)p;
            }
            *reinterpret_cast<bf16x4*>(&pt[wave][l16][half * 16 + quad * 4]) = pk;
        }
        bf16x8 pf = *reinterpret_cast<const bf16x8*>(&pt[wave][l16][quad * 8]);
#pragma unroll
        for (int nf = 0; nf < 4; ++nf) {
            const int rowv = nf * 16 + l16;
            const int pv = quad ^ (rowv & 3);
            bf16x8 vf = *reinterpret_cast<const bf16x8*>(&Vs[cur][rowv * 32 + pv * 8]);
            o[nf] = __builtin_amdgcn_mfma_f32_16x16x32_bf16(pf, vf, o[nf], 0, 0, 0);
        }
        asm volatile("" ::: "memory");
        __builtin_amdgcn_s_barrier();
        asm volatile("" ::: "memory");
    }

    sum += __shfl_xor(sum, 16, 64);
    sum += __shfl_xor(sum, 32, 64);
    if (quad == 0) sums_l[wave][l16] = sum;   // wave-local, no barrier
    float inv_l[4];
#pragma unroll
    for (int r = 0; r < 4; ++r) inv_l[r] = 1.0f / sums_l[wave][quad * 4 + r];
#pragma unroll
    for (int nf = 0; nf < 4; ++nf)
#pragma unroll
        for (int r = 0; r < 4; ++r) {
            int qr = q0 + quad * 4 + r;
            A[((size_t)(b * S_ + qr)) * HID_ + h * HD_ + nf * 16 + l16] =
                __float2bfloat16(o[nf][r] * inv_l[r]);
        }
}

// ---------------------------------------------------------------------------
// Output projection: 128x64 tile, BK=32. A operand: glds16 staging (r20
// exact). B operand (Wo): fp32 reg-load + cvt + swizzled ds_write, with
// next-tile prefetch. Direct fp32 stores.
// ---------------------------------------------------------------------------
__global__ __launch_bounds__(256) void out_proj(
    const bf16_t* __restrict__ Ain, const float* __restrict__ Wo,
    float* __restrict__ out)
{
    __shared__ __align__(16) bf16_t As[128 * 32];  // 8 KB
    __shared__ __align__(16) bf16_t Bs[64 * 32];   // 4 KB
    const int tid = threadIdx.x;
    const int wave = tid >> 6, lane = tid & 63;
    const int quad = lane >> 4, l16 = lane & 15;
    const int m0 = blockIdx.x * 128, n0 = blockIdx.y * 64;

    // B staging: row brow (64), chunk bchunk (4 x 8 cols)
    const int brow = tid >> 2, bchunk = tid & 3;
    const int bpc = (bchunk ^ ((brow >> 1) & 3)) * 8;
    const float* worow = Wo + (size_t)(n0 + brow) * HID_ + bchunk * 8;

    float4 cb0, cb1;
    cb0 = *reinterpret_cast<const float4*>(worow + 0);
    cb1 = *reinterpret_cast<const float4*>(worow + 4);

    f32x4 acc[2][4] = {};
    for (int t = 0; t < 16; ++t) {
        const int k0 = t * 32;
        // A: async glds16 staging (bf16 input, unchanged)
#pragma unroll
        for (int rr = 0; rr < 2; ++rr) {
            int slot = rr * 256 + tid;
            int row = slot >> 2;
            int l = (slot & 3) ^ ((row >> 1) & 3);
            glds16(Ain + (size_t)(m0 + row) * HID_ + k0 + l * 8, As + slot * 8);
        }
        // B: prefetch next, deposit current
        float4 nb0, nb1;
        if (t + 1 < 16) {
            const int k1 = (t + 1) * 32;
            nb0 = *reinterpret_cast<const float4*>(worow + k1 + 0);
            nb1 = *reinterpret_cast<const float4*>(worow + k1 + 4);
        }
        *reinterpret_cast<bf16x8*>(&Bs[brow * 32 + bpc]) = cvt8(cb0, cb1);
        __syncthreads();

        bf16x8 af[2], bfr[4];
#pragma unroll
        for (int i = 0; i < 2; ++i) {
            int ra = wave * 32 + i * 16 + l16;
            int pa = quad ^ ((ra >> 1) & 3);
            af[i] = *reinterpret_cast<const bf16x8*>(&As[ra * 32 + pa * 8]);
        }
#pragma unroll
        for (int i = 0; i < 4; ++i) {
            int rb = i * 16 + l16;
            int pb = quad ^ ((rb >> 1) & 3);
            bfr[i] = *reinterpret_cast<const bf16x8*>(&Bs[rb * 32 + pb * 8]);
        }
#pragma unroll
        for (int mi = 0; mi < 2; ++mi)
#pragma unroll
            for (int ni = 0; ni < 4; ++ni)
                acc[mi][ni] = __builtin_amdgcn_mfma_f32_16x16x32_bf16(af[mi], bfr[ni], acc[mi][ni], 0, 0, 0);
        __syncthreads();
        cb0 = nb0; cb1 = nb1;
    }
#pragma unroll
    for (int mi = 0; mi < 2; ++mi)
#pragma unroll
        for (int ni = 0; ni < 4; ++ni)
#pragma unroll
            for (int r = 0; r < 4; ++r) {
                int m = m0 + wave * 32 + mi * 16 + quad * 4 + r;
                int n = n0 + ni * 16 + l16;
                out[(size_t)m * HID_ + n] = acc[mi][ni][r];
            }
}

// ---------------------------------------------------------------------------
extern "C" void kernel_launch(void* const* d_in, const int* in_sizes, int n_in,
                              void* d_out, int out_size, void* d_ws, size_t ws_size,
                              hipStream_t stream)
{
    const float* X  = (const float*)d_in[0];
    // d_in[1] = position_ids (broadcast arange(S); pos derived from s index)
    const float* Wq = (const float*)d_in[2];
    const float* Wk = (const float*)d_in[3];
    const float* Wv = (const float*)d_in[4];
    const float* Wo = (const float*)d_in[5];

    char* ws = (char*)d_ws;
    const size_t elems = (size_t)B_ * NH_ * S_ * HD_;   // 4,194,304
    bf16_t* Q  = (bf16_t*)ws;
    bf16_t* K  = Q + elems;
    bf16_t* Vt = K + elems;
    bf16_t* A  = Vt + elems;            // ~33.5 MB total

    qkv_gemm<<<768, 256, 0, stream>>>(X, Wq, Wk, Wv, Q, K, Vt);
    attn_mfma<<<1024, 256, 0, stream>>>(Q, K, Vt, A);
    out_proj<<<dim3(64, 8), 256, 0, stream>>>(A, Wo, (float*)d_out);
}

// Round 13
// 124.724 us; speedup vs baseline: 1.0799x; 1.0799x over previous
//
#include <hip/hip_runtime.h>
#include <hip/hip_bf16.h>
#include <math.h>

// MimiAttention: B=4, S=2048, HID=512, NH=8, HD=64, SW=250, theta=10000
// Round 24: revert r23 (cvt-fusion: reg-staged fp32+cvt costs ~26% on GEMM
// staging vs glds16 DMA (m151) + 12x fp32 re-read; qkv 25->34us, net +9).
// r20 structure restored (125.6 verified). attn only: triple-buffered K/V
// staging (prefetch depth 2: stage t+2, steady vmcnt(4), tail vmcnt(2)/(0),
// same 2 barriers/tile; LDS 29.3KB -> 5 blocks/CU) + s_setprio(1/0) around
// QK and PV MFMA clusters (T5; m191 +4-7% attn with phase-diverse blocks).
// cvt/qkv/out = r20 byte-identical.

#define B_   4
#define S_   2048
#define HID_ 512
#define NH_  8
#define HD_  64
#define SW_  250

typedef __bf16 bf16x8 __attribute__((ext_vector_type(8)));
typedef __bf16 bf16x4 __attribute__((ext_vector_type(4)));
typedef float f32x4 __attribute__((ext_vector_type(4)));
using bf16_t = __hip_bfloat16;
typedef unsigned int u32;

// async global->LDS, 16 B per lane (wave-uniform base + lane*16 semantics)
__device__ __forceinline__ void glds16(const void* g, void* l) {
    __builtin_amdgcn_global_load_lds(
        (const __attribute__((address_space(1))) u32*)g,
        (__attribute__((address_space(3))) u32*)l, 16, 0, 0);
}

// ---------------------------------------------------------------------------
// One fused fp32->bf16 convert pass. 2048 elems/block.
// ---------------------------------------------------------------------------
__global__ __launch_bounds__(256) void cvt_all(
    const float* __restrict__ X,  const float* __restrict__ Wq,
    const float* __restrict__ Wk, const float* __restrict__ Wv,
    const float* __restrict__ Wo,
    bf16_t* __restrict__ Xb, bf16_t* __restrict__ Wcat, bf16_t* __restrict__ Wob)
{
    const int blk = blockIdx.x;
    const float* s; bf16_t* d; size_t base;
    if (blk < 2048)      { s = X;  d = Xb;            base = (size_t)blk * 2048; }
    else if (blk < 2176) { s = Wq; d = Wcat;          base = (size_t)(blk - 2048) * 2048; }
    else if (blk < 2304) { s = Wk; d = Wcat + 262144; base = (size_t)(blk - 2176) * 2048; }
    else if (blk < 2432) { s = Wv; d = Wcat + 524288; base = (size_t)(blk - 2304) * 2048; }
    else                 { s = Wo; d = Wob;           base = (size_t)(blk - 2432) * 2048; }
    size_t i = base + (size_t)threadIdx.x * 8;
    float4 a = *reinterpret_cast<const float4*>(s + i);
    float4 b = *reinterpret_cast<const float4*>(s + i + 4);
    bf16x8 r;
    r[0] = (__bf16)a.x; r[1] = (__bf16)a.y; r[2] = (__bf16)a.z; r[3] = (__bf16)a.w;
    r[4] = (__bf16)b.x; r[5] = (__bf16)b.y; r[6] = (__bf16)b.z; r[7] = (__bf16)b.w;
    *reinterpret_cast<bf16x8*>(d + i) = r;
}

// ---------------------------------------------------------------------------
// Fused QKV GEMM (r20 exact): 128x128 tile, BK=32, XOR-swizzled slots,
// RoPE epilogue, V transposed. 768 1-D blocks, XCD-chunked. Double-buffered
// staging, counted vmcnt(4), sched_barrier(0) fences.
// ---------------------------------------------------------------------------
__global__ __launch_bounds__(256) void qkv_gemm(
    const bf16_t* __restrict__ Xb, const bf16_t* __restrict__ Wcat,
    bf16_t* __restrict__ Q, bf16_t* __restrict__ Kbuf, bf16_t* __restrict__ Vt)
{
    __shared__ __align__(16) char smem_raw[34816];  // 32KB dbuf stage / 34KB epi
    bf16_t* const sm = (bf16_t*)smem_raw;
    const int tid = threadIdx.x;
    const int wave = tid >> 6, lane = tid & 63;
    const int quad = lane >> 4, l16 = lane & 15;
    const int wm = wave & 1, wn = wave >> 1;

    const int g = blockIdx.x;
    const int xcd = g & 7, slot = g >> 3;          // slot in [0,96)
    const int mi = xcd * 8 + (slot & 7);           // [0,64)
    const int ni = slot >> 3;                      // [0,12)
    const int m0 = mi * 128, n0 = ni * 128;

    const int srow0 = tid >> 2,           sl0 = (tid & 3) ^ ((srow0 >> 1) & 3);
    const int srow1 = (256 + tid) >> 2,   sl1 = ((256 + tid) & 3) ^ ((srow1 >> 1) & 3);

    glds16(Xb   + (size_t)(m0 + srow0) * HID_ + sl0 * 8, sm + tid * 8);
    glds16(Wcat + (size_t)(n0 + srow0) * HID_ + sl0 * 8, sm + 4096 + tid * 8);
    glds16(Xb   + (size_t)(m0 + srow1) * HID_ + sl1 * 8, sm + (256 + tid) * 8);
    glds16(Wcat + (size_t)(n0 + srow1) * HID_ + sl1 * 8, sm + 4096 + (256 + tid) * 8);

    f32x4 acc[4][4] = {};
    for (int t = 0; t < 16; ++t) {
        const int curo = (t & 1) * 8192;
        if (t + 1 < 16) {
            const int nxto = curo ^ 8192;
            const int k1 = (t + 1) * 32;
            glds16(Xb   + (size_t)(m0 + srow0) * HID_ + k1 + sl0 * 8, sm + nxto + tid * 8);
            glds16(Wcat + (size_t)(n0 + srow0) * HID_ + k1 + sl0 * 8, sm + nxto + 4096 + tid * 8);
            glds16(Xb   + (size_t)(m0 + srow1) * HID_ + k1 + sl1 * 8, sm + nxto + (256 + tid) * 8);
            glds16(Wcat + (size_t)(n0 + srow1) * HID_ + k1 + sl1 * 8, sm + nxto + 4096 + (256 + tid) * 8);
            asm volatile("s_waitcnt vmcnt(4)" ::: "memory");
        } else {
            asm volatile("s_waitcnt vmcnt(0)" ::: "memory");
        }
        __builtin_amdgcn_sched_barrier(0);
        __builtin_amdgcn_s_barrier();
        __builtin_amdgcn_sched_barrier(0);

        bf16x8 af[4], bfr[4];
#pragma unroll
        for (int i = 0; i < 4; ++i) {
            int ra = wm * 64 + i * 16 + l16;
            int rb = wn * 64 + i * 16 + l16;
            int pa = quad ^ ((ra >> 1) & 3);
            int pb = quad ^ ((rb >> 1) & 3);
            af[i]  = *reinterpret_cast<const bf16x8*>(sm + curo + ra * 32 + pa * 8);
            bfr[i] = *reinterpret_cast<const bf16x8*>(sm + curo + 4096 + rb * 32 + pb * 8);
        }
#pragma unroll
        for (int mi2 = 0; mi2 < 4; ++mi2)
#pragma unroll
            for (int ni2 = 0; ni2 < 4; ++ni2)
                acc[mi2][ni2] = __builtin_amdgcn_mfma_f32_16x16x32_bf16(af[mi2], bfr[ni2], acc[mi2][ni2], 0, 0, 0);
        asm volatile("" ::: "memory");
        __builtin_amdgcn_sched_barrier(0);
        __builtin_amdgcn_s_barrier();
        __builtin_amdgcn_sched_barrier(0);
    }

    // ---- epilogue via wave-private 64x68 bf16 LDS tile (4352 elems/wave) ----
    const int seg = n0 >> 9;                      // 0=Q 1=K 2=V
    const int hh = ((n0 & 511) + wn * 64) >> 6;
    bf16_t* wt = sm + wave * 4352;
    const int mbase = m0 + wm * 64;
    const int bb = mbase >> 11;
    const int sbase = mbase & (S_ - 1);

    if (seg < 2) {
        const float qs = (seg == 0) ? 0.125f : 1.0f;
        const float c = 0.41524101186f;           // log2(10000)/32
        float inv0 = exp2f(-(float)l16 * c);
        float inv1 = exp2f(-(float)(l16 + 16) * c);
#pragma unroll
        for (int mi2 = 0; mi2 < 4; ++mi2)
#pragma unroll
            for (int r = 0; r < 4; ++r) {
                int lrow = mi2 * 16 + quad * 4 + r;
                float sf = (float)(sbase + lrow);
#pragma unroll
                for (int ip = 0; ip < 2; ++ip) {
                    float sn, cs_;
                    __sincosf(sf * (ip ? inv1 : inv0), &sn, &cs_);
                    float x1 = acc[mi2][ip][r], x2 = acc[mi2][ip + 2][r];
                    wt[lrow * 68 + ip * 16 + l16]      = __float2bfloat16((x1 * cs_ - x2 * sn) * qs);
                    wt[lrow * 68 + ip * 16 + l16 + 32] = __float2bfloat16((x2 * cs_ + x1 * sn) * qs);
                }
            }
        bf16_t* Y = (seg == 0) ? Q : Kbuf;
#pragma unroll
        for (int it = 0; it < 8; ++it) {
            int e = it * 64 + lane;
            int sr = e >> 3, doff = (e & 7) * 8;
            size_t g2 = ((size_t)(bb * NH_ + hh) * S_ + sbase + sr) * HD_ + doff;
            *reinterpret_cast<bf16x8*>(Y + g2) =
                *reinterpret_cast<const bf16x8*>(wt + sr * 68 + doff);
        }
    } else {
#pragma unroll
        for (int mi2 = 0; mi2 < 4; ++mi2)
#pragma unroll
            for (int ni2 = 0; ni2 < 4; ++ni2)
#pragma unroll
                for (int r = 0; r < 4; ++r)
                    wt[(ni2 * 16 + l16) * 68 + mi2 * 16 + quad * 4 + r] =
                        __float2bfloat16(acc[mi2][ni2][r]);
#pragma unroll
        for (int it = 0; it < 8; ++it) {
            int e = it * 64 + lane;
            int d = e >> 3, soff = (e & 7) * 8;
            size_t g2 = ((size_t)(bb * NH_ + hh) * HD_ + d) * S_ + sbase + soff;
            *reinterpret_cast<bf16x8*>(Vt + g2) =
                *reinterpret_cast<const bf16x8*>(wt + d * 68 + soff);
        }
    }
}

// ---------------------------------------------------------------------------
// Attention: block = 64 q-rows, TRIPLE-buffered K/V staging (prefetch depth
// 2: stage t+2, steady vmcnt(4), tail vmcnt(2)/vmcnt(0); 2 barriers/tile
// unchanged — buf (t+2)%3 was last read at t-1, whose closing barrier
// precedes the stage). s_setprio(1/0) around QK and PV MFMA clusters.
// One-pass no-max softmax. 1024 blocks, XCD-chunked.
// ---------------------------------------------------------------------------
__global__ __launch_bounds__(256) void attn_mfma(
    const bf16_t* __restrict__ Q, const bf16_t* __restrict__ K,
    const bf16_t* __restrict__ Vt, bf16_t* __restrict__ A)
{
    __shared__ __align__(16) __bf16 Ks[3][32 * 64];   // 3 x 4 KB
    __shared__ __align__(16) __bf16 Vs[3][64 * 32];   // 3 x 4 KB
    __shared__ __align__(16) __bf16 pt[4][16][40];    // per-wave P, 5 KB
    __shared__ float sums_l[4][16];
    const int tid = threadIdx.x;
    const int wave = tid >> 6, lane = tid & 63;
    const int quad = lane >> 4, l16 = lane & 15;

    const int g = blockIdx.x;
    const int xcd = g & 7, slot = g >> 3;          // slot in [0,128)
    const int bh = xcd * 4 + (slot >> 5);          // [0,32)
    const int qt = slot & 31;                      // q-block of 64 rows
    const int b = bh >> 3, h = bh & 7;
    const int q0b = qt * 64;
    const int q0 = q0b + wave * 16;

    const size_t bh_  = (size_t)(b * NH_ + h) * S_;
    const size_t bhd = (size_t)(b * NH_ + h) * HD_;

    bf16x8 qf0, qf1;
    {
        const bf16_t* qp = Q + (bh_ + q0 + l16) * HD_ + quad * 8;
        qf0 = *reinterpret_cast<const bf16x8*>(qp);
        qf1 = *reinterpret_cast<const bf16x8*>(qp + 32);
    }
    const int kstartB = (q0b > SW_) ? ((q0b - SW_) & ~31) : 0;
    const int ntB = (q0b + 95 - kstartB) >> 5;     // 2..12, block-uniform
    const int qq = q0 + l16;

    const int krow = tid >> 3, kl = (tid & 7) ^ (krow & 7);   // K stage addr
    const int vrow = tid >> 2, vl = (tid & 3) ^ (vrow & 3);   // V stage addr

    // prologue: stage tiles 0 and 1 (ntB >= 2 always)
    glds16(K  + (bh_ + kstartB + krow) * HD_ + kl * 8, &Ks[0][tid * 8]);
    glds16(Vt + (bhd + vrow) * S_ + kstartB + vl * 8, &Vs[0][tid * 8]);
    {
        const int kb1 = kstartB + 32;
        glds16(K  + (bh_ + kb1 + krow) * HD_ + kl * 8, &Ks[1][tid * 8]);
        glds16(Vt + (bhd + vrow) * S_ + kb1 + vl * 8, &Vs[1][tid * 8]);
    }

    float sum = 0.f;
    f32x4 o[4] = {};
    int cur = 0, stg = 2;                          // compute buf, stage buf
    for (int t = 0; t < ntB; ++t) {
        const int kb = kstartB + t * 32;
        if (t + 2 < ntB) {
            const int kb2 = kb + 64;
            glds16(K  + (bh_ + kb2 + krow) * HD_ + kl * 8, &Ks[stg][tid * 8]);
            glds16(Vt + (bhd + vrow) * S_ + kb2 + vl * 8, &Vs[stg][tid * 8]);
            asm volatile("s_waitcnt vmcnt(4)" ::: "memory");  // t landed; t+1,t+2 in flight
        } else if (t + 1 < ntB) {
            asm volatile("s_waitcnt vmcnt(2)" ::: "memory");  // t landed; t+1 in flight
        } else {
            asm volatile("s_waitcnt vmcnt(0)" ::: "memory");
        }
        __builtin_amdgcn_s_barrier();
        asm volatile("" ::: "memory");

#pragma unroll
        for (int half = 0; half < 2; ++half) {
            const int rowt = half * 16 + l16;
            const int p0 = quad ^ (rowt & 7);
            const int p1 = (quad ^ 4) ^ (rowt & 7);
            bf16x8 k0 = *reinterpret_cast<const bf16x8*>(&Ks[cur][rowt * 64 + p0 * 8]);
            bf16x8 k1 = *reinterpret_cast<const bf16x8*>(&Ks[cur][rowt * 64 + p1 * 8]);
            f32x4 z = {};
            __builtin_amdgcn_s_setprio(1);
            z = __builtin_amdgcn_mfma_f32_16x16x32_bf16(k0, qf0, z, 0, 0, 0);
            z = __builtin_amdgcn_mfma_f32_16x16x32_bf16(k1, qf1, z, 0, 0, 0);
            __builtin_amdgcn_s_setprio(0);
            const int kbase = kb + half * 16 + quad * 4;
            bf16x4 pk;
#pragma unroll
            for (int r = 0; r < 4; ++r) {
                int key = kbase + r;
                bool keep = (key <= qq) && (qq - key <= SW_);
                float p = keep ? __expf(z[r]) : 0.f;
                sum += p;
                pk[r] = (__bf16)p;
            }
            *reinterpret_cast<bf16x4*>(&pt[wave][l16][half * 16 + quad * 4]) = pk;
        }
        bf16x8 pf = *reinterpret_cast<const bf16x8*>(&pt[wave][l16][quad * 8]);
        __builtin_amdgcn_s_setprio(1);
#pragma unroll
        for (int nf = 0; nf < 4; ++nf) {
            const int rowv = nf * 16 + l16;
            const int pv = quad ^ (rowv & 3);
            bf16x8 vf = *reinterpret_cast<const bf16x8*>(&Vs[cur][rowv * 32 + pv * 8]);
            o[nf] = __builtin_amdgcn_mfma_f32_16x16x32_bf16(pf, vf, o[nf], 0, 0, 0);
        }
        __builtin_amdgcn_s_setprio(0);
        asm volatile("" ::: "memory");
        __builtin_amdgcn_s_barrier();
        asm volatile("" ::: "memory");
        cur = (cur == 2) ? 0 : cur + 1;
        stg = (stg == 2) ? 0 : stg + 1;
    }

    sum += __shfl_xor(sum, 16, 64);
    sum += __shfl_xor(sum, 32, 64);
    if (quad == 0) sums_l[wave][l16] = sum;   // wave-local, no barrier
    float inv_l[4];
#pragma unroll
    for (int r = 0; r < 4; ++r) inv_l[r] = 1.0f / sums_l[wave][quad * 4 + r];
#pragma unroll
    for (int nf = 0; nf < 4; ++nf)
#pragma unroll
        for (int r = 0; r < 4; ++r) {
            int qr = q0 + quad * 4 + r;
            A[((size_t)(b * S_ + qr)) * HID_ + h * HD_ + nf * 16 + l16] =
                __float2bfloat16(o[nf][r] * inv_l[r]);
        }
}

// ---------------------------------------------------------------------------
// Output projection (r20 exact): 128x64 tile, BK=32, single-buffer
// __syncthreads K-loop, direct fp32 stores.
// ---------------------------------------------------------------------------
__global__ __launch_bounds__(256) void out_proj(
    const bf16_t* __restrict__ Ain, const bf16_t* __restrict__ Wob,
    float* __restrict__ out)
{
    __shared__ __align__(16) bf16_t As[128 * 32];  // 8 KB
    __shared__ __align__(16) bf16_t Bs[64 * 32];   // 4 KB
    const int tid = threadIdx.x;
    const int wave = tid >> 6, lane = tid & 63;
    const int quad = lane >> 4, l16 = lane & 15;
    const int m0 = blockIdx.x * 128, n0 = blockIdx.y * 64;

    f32x4 acc[2][4] = {};
    for (int k0 = 0; k0 < HID_; k0 += 32) {
#pragma unroll
        for (int rr = 0; rr < 2; ++rr) {
            int slot = rr * 256 + tid;
            int row = slot >> 2;
            int l = (slot & 3) ^ ((row >> 1) & 3);
            glds16(Ain + (size_t)(m0 + row) * HID_ + k0 + l * 8, As + slot * 8);
        }
        {
            int slot = tid;                        // 256 slots: one round
            int row = slot >> 2;
            int l = (slot & 3) ^ ((row >> 1) & 3);
            glds16(Wob + (size_t)(n0 + row) * HID_ + k0 + l * 8, Bs + slot * 8);
        }
        __syncthreads();
        bf16x8 af[2], bfr[4];
#pragma unroll
        for (int i = 0; i < 2; ++i) {
            int ra = wave * 32 + i * 16 + l16;
            int pa = quad ^ ((ra >> 1) & 3);
            af[i] = *reinterpret_cast<const bf16x8*>(&As[ra * 32 + pa * 8]);
        }
#pragma unroll
        for (int i = 0; i < 4; ++i) {
            int rb = i * 16 + l16;
            int pb = quad ^ ((rb >> 1) & 3);
            bfr[i] = *reinterpret_cast<const bf16x8*>(&Bs[rb * 32 + pb * 8]);
        }
#pragma unroll
        for (int mi = 0; mi < 2; ++mi)
#pragma unroll
            for (int ni = 0; ni < 4; ++ni)
                acc[mi][ni] = __builtin_amdgcn_mfma_f32_16x16x32_bf16(af[mi], bfr[ni], acc[mi][ni], 0, 0, 0);
        __syncthreads();
    }
#pragma unroll
    for (int mi = 0; mi < 2; ++mi)
#pragma unroll
        for (int ni = 0; ni < 4; ++ni)
#pragma unroll
            for (int r = 0; r < 4; ++r) {
                int m = m0 + wave * 32 + mi * 16 + quad * 4 + r;
                int n = n0 + ni * 16 + l16;
                out[(size_t)m * HID_ + n] = acc[mi][ni][r];
            }
}

// ---------------------------------------------------------------------------
extern "C" void kernel_launch(void* const* d_in, const int* in_sizes, int n_in,
                              void* d_out, int out_size, void* d_ws, size_t ws_size,
                              hipStream_t stream)
{
    const float* X  = (const float*)d_in[0];
    // d_in[1] = position_ids (broadcast arange(S); pos derived from s index)
    const float* Wq = (const float*)d_in[2];
    const float* Wk = (const float*)d_in[3];
    const float* Wv = (const float*)d_in[4];
    const float* Wo = (const float*)d_in[5];

    char* ws = (char*)d_ws;
    const size_t elems = (size_t)B_ * NH_ * S_ * HD_;   // 4,194,304
    const size_t wsz   = (size_t)HID_ * HID_;           // 262,144
    bf16_t* Q    = (bf16_t*)ws;
    bf16_t* K    = Q + elems;
    bf16_t* Vt   = K + elems;
    bf16_t* Xb   = Vt + elems;          // aliased: A overwrites Xb after qkv
    bf16_t* A    = Xb;
    bf16_t* Wcat = Xb + elems;
    bf16_t* Wob  = Wcat + 3 * wsz;      // total ~35.6 MB

    cvt_all<<<2560, 256, 0, stream>>>(X, Wq, Wk, Wv, Wo, Xb, Wcat, Wob);
    qkv_gemm<<<768, 256, 0, stream>>>(Xb, Wcat, Q, K, Vt);
    attn_mfma<<<1024, 256, 0, stream>>>(Q, K, Vt, A);
    out_proj<<<dim3(64, 8), 256, 0, stream>>>(A, Wob, (float*)d_out);
}